// Round 15
// baseline (277.938 us; speedup 1.0000x reference)
//
#include <hip/hip_runtime.h>
#include <math.h>

#define B_ 8
#define N_ 1024
#define F_ 768
#define H_ 12
#define DH_ 64
#define MH_ 3072
#define MROWS (B_ * N_)

typedef unsigned short u16;
typedef unsigned int u32;
typedef __bf16 bf16x8 __attribute__((ext_vector_type(8)));
typedef float f32x4 __attribute__((ext_vector_type(4)));

__device__ inline f32x4 mfma16(bf16x8 a, bf16x8 b, f32x4 c) {
  return __builtin_amdgcn_mfma_f32_16x16x32_bf16(a, b, c, 0, 0, 0);
}

__device__ inline u16 f2bu(float f) {  // float -> bf16 bits, RNE
  u32 b = __builtin_bit_cast(u32, f);
  b += 0x7fffu + ((b >> 16) & 1u);
  return (u16)(b >> 16);
}
__device__ inline float bu2f(u16 u) {
  u32 x = ((u32)u) << 16;
  return __builtin_bit_cast(float, x);
}
// tanh-form GELU, max abs err ~3e-4 vs exact erf form (well under bf16 ulp here)
__device__ inline float gelu_f(float x) {
  float u = x * (0.7978845608028654f + 0.035677408136300125f * x * x);
  float t = exp2f(-2.8853900817779268f * fabsf(u));   // e^{-2|u|}
  float th = (1.0f - t) / (1.0f + t);                 // tanh(|u|)
  th = copysignf(th, u);
  return 0.5f * x * (1.0f + th);
}

#define AS1 __attribute__((address_space(1)))
#define AS3 __attribute__((address_space(3)))
__device__ inline void glds16(const void* g, void* l) {
  __builtin_amdgcn_global_load_lds((const AS1 void*)g, (AS3 void*)l, 16, 0, 0);
}

// ---------------- fused weight prep: 6 transposes fp32->bf16^T ---------------
__global__ __launch_bounds__(256) void prep_weights(
    const float* __restrict__ Wq, const float* __restrict__ Wk,
    const float* __restrict__ Wv, const float* __restrict__ Wo,
    const float* __restrict__ W1, const float* __restrict__ W2,
    u16* __restrict__ Wqkvt, u16* __restrict__ Wot,
    u16* __restrict__ W1t, u16* __restrict__ W2t) {
  __shared__ float tile[64][65];
  int z = blockIdx.z;
  const float* in; u16* out; int R, C;
  if (z == 0)      { in = Wq; out = Wqkvt;                       R = 768;  C = 768; }
  else if (z == 1) { in = Wk; out = Wqkvt + 768 * 768;           R = 768;  C = 768; }
  else if (z == 2) { in = Wv; out = Wqkvt + 2 * 768 * 768;       R = 768;  C = 768; }
  else if (z == 3) { in = Wo; out = Wot;                         R = 768;  C = 768; }
  else if (z == 4) { in = W1; out = W1t;                         R = 768;  C = 3072; }
  else             { in = W2; out = W2t;                         R = 3072; C = 768; }
  int r0 = blockIdx.y << 6, c0 = blockIdx.x << 6;
  if (r0 >= R || c0 >= C) return;
  int t = threadIdx.x;
#pragma unroll
  for (int i = 0; i < 16; ++i) {
    int idx = t + (i << 8);
    int r = idx >> 6, c = idx & 63;
    tile[r][c] = in[(size_t)(r0 + r) * C + (c0 + c)];
  }
  __syncthreads();
#pragma unroll
  for (int i = 0; i < 16; ++i) {
    int idx = t + (i << 8);
    int rr = idx >> 6, cc = idx & 63;
    out[(size_t)(c0 + rr) * R + (r0 + cc)] = f2bu(tile[cc][rr]);
  }
}

// ---------------- LayerNorm (row=768) fp32|bf16 -> bf16 ----------------------
__device__ inline float ldf(const float* p) { return *p; }
__device__ inline float ldf(const u16* p) { return bu2f(*p); }

template <typename Tin>
__global__ __launch_bounds__(256) void ln_to_bf16(
    const Tin* __restrict__ X, const float* __restrict__ gw,
    const float* __restrict__ bw, u16* __restrict__ Y) {
  int row = blockIdx.x;
  int t = threadIdx.x;
  const Tin* xr = X + (size_t)row * F_;
  float v0 = ldf(&xr[t]), v1 = ldf(&xr[t + 256]), v2 = ldf(&xr[t + 512]);
  float s = v0 + v1 + v2;
  float ss = v0 * v0 + v1 * v1 + v2 * v2;
#pragma unroll
  for (int off = 1; off < 64; off <<= 1) {
    s += __shfl_xor(s, off, 64);
    ss += __shfl_xor(ss, off, 64);
  }
  __shared__ float red[8];
  int wid = t >> 6, lane = t & 63;
  if (lane == 0) { red[wid] = s; red[4 + wid] = ss; }
  __syncthreads();
  s = red[0] + red[1] + red[2] + red[3];
  ss = red[4] + red[5] + red[6] + red[7];
  float mu = s * (1.0f / F_);
  float var = ss * (1.0f / F_) - mu * mu;
  float rstd = rsqrtf(var + 1e-5f);
  u16* yr = Y + (size_t)row * F_;
  yr[t] = f2bu((v0 - mu) * rstd * gw[t] + bw[t]);
  yr[t + 256] = f2bu((v1 - mu) * rstd * gw[t + 256] + bw[t + 256]);
  yr[t + 512] = f2bu((v2 - mu) * rstd * gw[t + 512] + bw[t + 512]);
}

// ---------------- GEMM A: 128x128 block, 4 waves of 64x64, BK=64 -------------
// r14 structure (counted-vmcnt, 2-slot ring, 8 glds/stage/wave). Used for
// qkv (MODE 0) and ffn1 (MODE 2) where the grid is large/balanced.
template <int MODE>
__global__ __launch_bounds__(256, 2) void gemm_t(
    const u16* __restrict__ A, const u16* __restrict__ Bt,
    const float* __restrict__ b0, const float* __restrict__ b1,
    const float* __restrict__ b2, void* __restrict__ outp,
    const void* __restrict__ resid, int Ndim, int Kdim, float qscale) {
  __shared__ __attribute__((aligned(16))) u16 As[2][2][128][32];  // [buf][kh]
  __shared__ __attribute__((aligned(16))) u16 Bs[2][2][128][32];
  int t = threadIdx.x;
  int lane = t & 63, wid = t >> 6;

  int nwg = gridDim.x;
  int q8 = nwg >> 3;
  int bid = blockIdx.x;
  int swz = (bid & 7) * q8 + (bid >> 3);
  int nnt = Ndim >> 7;           // 128-wide col tiles
  int mt = swz / nnt, nt = swz - mt * nnt;
  int row0 = mt << 7, col0 = nt << 7;

  int wr = (wid >> 1) << 6;      // 0 / 64
  int wc = (wid & 1) << 6;       // 0 / 64
  int lr = lane & 15, lk = (lane >> 4) << 3;
  int rbase = (lane >> 4) << 2;
  f32x4 zero = {0.f, 0.f, 0.f, 0.f};
  f32x4 acc[4][4];
#pragma unroll
  for (int m = 0; m < 4; ++m)
#pragma unroll
    for (int n = 0; n < 4; ++n) acc[m][n] = zero;

  int srow = (wid << 5) + (lane >> 2);
  int scol = (lane & 3) << 3;
  const u16* Ag = A + (size_t)(row0 + srow) * Kdim + scol;
  const u16* Bg = Bt + (size_t)(col0 + srow) * Kdim + scol;
  char* AsB = (char*)&As[0][0][0][0] + (wid << 11);
  char* BsB = (char*)&Bs[0][0][0][0] + (wid << 11);

  auto STAGE = [&](int buf, int kt) {   // 8 glds per wave
    int ab = buf << 14;
#pragma unroll
    for (int kh = 0; kh < 2; ++kh) {
#pragma unroll
      for (int i = 0; i < 2; ++i) {
        glds16(Ag + (size_t)(i << 4) * Kdim + kt + (kh << 5),
               AsB + ab + (kh << 13) + (i << 10));
        glds16(Bg + (size_t)(i << 4) * Kdim + kt + (kh << 5),
               BsB + ab + (kh << 13) + (i << 10));
      }
    }
  };

  int nk = Kdim >> 6;
  STAGE(0, 0);
  if (nk > 1) STAGE(1, 64);

  for (int ki = 0; ki < nk; ++ki) {
    int buf = ki & 1;
    if (ki + 1 < nk) {
      asm volatile("s_waitcnt vmcnt(8)" ::: "memory");
    } else {
      asm volatile("s_waitcnt vmcnt(0)" ::: "memory");
    }
    __builtin_amdgcn_sched_barrier(0);
    __builtin_amdgcn_s_barrier();           // bar1: tile ki resident
    __builtin_amdgcn_sched_barrier(0);
    bf16x8 af[2][4], bfr[2][4];
#pragma unroll
    for (int h = 0; h < 2; ++h) {
#pragma unroll
      for (int m = 0; m < 4; ++m)
        af[h][m] = *(const bf16x8*)&As[buf][h][wr + (m << 4) + lr][lk];
#pragma unroll
      for (int n = 0; n < 4; ++n)
        bfr[h][n] = *(const bf16x8*)&Bs[buf][h][wc + (n << 4) + lr][lk];
    }
    __builtin_amdgcn_sched_barrier(0);
    __builtin_amdgcn_s_barrier();           // bar2: all reads issued
    __builtin_amdgcn_sched_barrier(0);
    if (ki + 2 < nk) STAGE(buf, (ki + 2) << 6);
    __builtin_amdgcn_s_setprio(1);
#pragma unroll
    for (int h = 0; h < 2; ++h)
#pragma unroll
      for (int m = 0; m < 4; ++m)
#pragma unroll
        for (int n = 0; n < 4; ++n) acc[m][n] = mfma16(af[h][m], bfr[h][n], acc[m][n]);
    __builtin_amdgcn_s_setprio(0);
  }

#pragma unroll
  for (int n = 0; n < 4; ++n) {
    int col = col0 + wc + (n << 4) + lr;
    float bc;
    int sub = 0, hh = 0, dh = 0;
    float sc = 1.0f;
    if constexpr (MODE == 0) {
      sub = (col >= 1536) ? 2 : (col >= 768 ? 1 : 0);
      int c = col - sub * 768;
      bc = (sub == 0) ? b0[c] : (sub == 1 ? b1[c] : b2[c]);
      hh = c >> 6; dh = c & 63;
      sc = (sub == 0) ? qscale : 1.0f;
    } else {
      bc = b0[col];
    }
#pragma unroll
    for (int m = 0; m < 4; ++m) {
#pragma unroll
      for (int r = 0; r < 4; ++r) {
        int row = row0 + wr + (m << 4) + rbase + r;
        float val = acc[m][n][r] + bc;
        if constexpr (MODE == 0) {
          int bb = row >> 10, nn = row & 1023;
          if (sub < 2) {
            ((u16*)outp)[(size_t)sub * 6291456 +
                         ((((size_t)bb * H_ + hh) << 10) + nn) * DH_ + dh] = f2bu(val * sc);
          } else {
            ((u16*)outp)[(size_t)2 * 6291456 +
                         ((((size_t)bb * H_ + hh) << 6) + dh) * 1024 + nn] = f2bu(val);
          }
        } else {
          ((u16*)outp)[(size_t)row * Ndim + col] = f2bu(gelu_f(val));
        }
      }
    }
  }
}

// ---------------- GEMM B: 128x64 block, 4 waves of 64x32, BK=64 --------------
// Counted-vmcnt port of the r12 geometry; 6 glds/stage/wave, vmcnt(6).
// Used for N=768 GEMMs (proj MODE 1, ffn2 MODE 3): 768 blocks @ 3/CU =
// exactly one balanced round (vs 384 @ 2/CU imbalanced at 128x128).
template <int MODE>
__global__ __launch_bounds__(256, 3) void gemm_s(
    const u16* __restrict__ A, const u16* __restrict__ Bt,
    const float* __restrict__ bias, void* __restrict__ outp,
    const void* __restrict__ resid, int Ndim, int Kdim) {
  __shared__ __attribute__((aligned(16))) u16 As[2][2][128][32];  // [buf][kh]
  __shared__ __attribute__((aligned(16))) u16 Bs[2][2][64][32];
  int t = threadIdx.x;
  int lane = t & 63, wid = t >> 6;

  int nwg = gridDim.x;
  int q8 = nwg >> 3;
  int bid = blockIdx.x;
  int swz = (bid & 7) * q8 + (bid >> 3);
  int nnt = Ndim >> 6;           // 64-wide col tiles
  int mt = swz / nnt, nt = swz - mt * nnt;
  int row0 = mt << 7, col0 = nt << 6;

  int wr = (wid >> 1) << 6;      // 0 / 64
  int wc = (wid & 1) << 5;       // 0 / 32
  int lr = lane & 15, lk = (lane >> 4) << 3;
  int rbase = (lane >> 4) << 2;
  f32x4 zero = {0.f, 0.f, 0.f, 0.f};
  f32x4 acc[4][2];
#pragma unroll
  for (int m = 0; m < 4; ++m)
#pragma unroll
    for (int n = 0; n < 2; ++n) acc[m][n] = zero;

  // A staging: wave w owns rows [w*32, w*32+32); 2 glds x 2 kh = 4
  // B staging: wave w owns rows [w*16, w*16+16); 1 glds x 2 kh = 2
  int sarow = (wid << 5) + (lane >> 2);
  int sbrow = (wid << 4) + (lane >> 2);
  int scol = (lane & 3) << 3;
  const u16* Ag = A + (size_t)(row0 + sarow) * Kdim + scol;
  const u16* Bg = Bt + (size_t)(col0 + sbrow) * Kdim + scol;
  char* AsB = (char*)&As[0][0][0][0] + (wid << 11);
  char* BsB = (char*)&Bs[0][0][0][0] + (wid << 10);

  auto STAGE = [&](int buf, int kt) {   // 6 glds per wave
    int ab = buf << 14, bb = buf << 13;
#pragma unroll
    for (int kh = 0; kh < 2; ++kh) {
#pragma unroll
      for (int i = 0; i < 2; ++i)
        glds16(Ag + (size_t)(i << 4) * Kdim + kt + (kh << 5),
               AsB + ab + (kh << 13) + (i << 10));
      glds16(Bg + kt + (kh << 5), BsB + bb + (kh << 12));
    }
  };

  int nk = Kdim >> 6;
  STAGE(0, 0);
  if (nk > 1) STAGE(1, 64);

  for (int ki = 0; ki < nk; ++ki) {
    int buf = ki & 1;
    if (ki + 1 < nk) {
      asm volatile("s_waitcnt vmcnt(6)" ::: "memory");
    } else {
      asm volatile("s_waitcnt vmcnt(0)" ::: "memory");
    }
    __builtin_amdgcn_sched_barrier(0);
    __builtin_amdgcn_s_barrier();           // bar1: tile ki resident
    __builtin_amdgcn_sched_barrier(0);
    bf16x8 af[2][4], bfr[2][2];
#pragma unroll
    for (int h = 0; h < 2; ++h) {
#pragma unroll
      for (int m = 0; m < 4; ++m)
        af[h][m] = *(const bf16x8*)&As[buf][h][wr + (m << 4) + lr][lk];
#pragma unroll
      for (int n = 0; n < 2; ++n)
        bfr[h][n] = *(const bf16x8*)&Bs[buf][h][wc + (n << 4) + lr][lk];
    }
    __builtin_amdgcn_sched_barrier(0);
    __builtin_amdgcn_s_barrier();           // bar2: all reads issued
    __builtin_amdgcn_sched_barrier(0);
    if (ki + 2 < nk) STAGE(buf, (ki + 2) << 6);
    __builtin_amdgcn_s_setprio(1);
#pragma unroll
    for (int h = 0; h < 2; ++h)
#pragma unroll
      for (int m = 0; m < 4; ++m)
#pragma unroll
        for (int n = 0; n < 2; ++n) acc[m][n] = mfma16(af[h][m], bfr[h][n], acc[m][n]);
    __builtin_amdgcn_s_setprio(0);
  }

#pragma unroll
  for (int n = 0; n < 2; ++n) {
    int col = col0 + wc + (n << 4) + lr;
    float bc = bias[col];
#pragma unroll
    for (int m = 0; m < 4; ++m) {
#pragma unroll
      for (int r = 0; r < 4; ++r) {
        int row = row0 + wr + (m << 4) + rbase + r;
        float val = acc[m][n][r] + bc;
        if constexpr (MODE == 1) {
          val += ((const float*)resid)[(size_t)row * Ndim + col];
          ((u16*)outp)[(size_t)row * Ndim + col] = f2bu(val);
        } else {
          val = gelu_f(val) + bu2f(((const u16*)resid)[(size_t)row * Ndim + col]);
          ((float*)outp)[(size_t)row * Ndim + col] = val;
        }
      }
    }
  }
}

// ---------------- flash attention: no-max softmax, KV chunk 64, T14 split ----
// Q pre-scaled by 1/sqrt(768)*log2(e). Q,K [bh][N][64], Vt [bh][64][N].
__global__ __launch_bounds__(256, 3) void attn_fwd(
    const u16* __restrict__ Q, const u16* __restrict__ K,
    const u16* __restrict__ Vt, u16* __restrict__ Aout) {
  __shared__ __attribute__((aligned(16))) u16 Ks[64][72];
  __shared__ __attribute__((aligned(16))) u16 Vs[64][72];
  __shared__ __attribute__((aligned(16))) u16 Ps[4][32][72];
  int t = threadIdx.x, lane = t & 63, wid = t >> 6;

  int bid = blockIdx.x;                 // 768 blocks
  int swz = (bid & 7) * 96 + (bid >> 3);
  int bh = swz >> 3;
  int qt = swz & 7;
  int q0 = (qt << 7) + (wid << 5);

  int lr = lane & 15, lk = (lane >> 4) << 3;
  int rbase = (lane >> 4) << 2;

  bf16x8 qf[2][2];
#pragma unroll
  for (int m = 0; m < 2; ++m)
#pragma unroll
    for (int ks = 0; ks < 2; ++ks)
      qf[m][ks] = *(const bf16x8*)&Q[((size_t)bh * N_ + q0 + (m << 4) + lr) * DH_ + (ks << 5) + lk];

  float lsum[2][4];
  f32x4 zero = {0.f, 0.f, 0.f, 0.f};
  f32x4 Oacc[2][4];
#pragma unroll
  for (int m = 0; m < 2; ++m) {
#pragma unroll
    for (int r = 0; r < 4; ++r) lsum[m][r] = 0.f;
#pragma unroll
    for (int nd = 0; nd < 4; ++nd) Oacc[m][nd] = zero;
  }

  int srow = t >> 3;            // 0..31
  int scol = (t & 7) << 3;      // 0..56
  const u16* Kg = K + ((size_t)bh * N_ + srow) * DH_ + scol;
  const u16* Vg = Vt + ((size_t)bh * DH_ + srow) * N_ + scol;

  uint4 kr0, kr1, vr0, vr1;
  auto LOADKV = [&](int kt) {
    kr0 = *(const uint4*)(Kg + (size_t)(kt << 6) * DH_);
    kr1 = *(const uint4*)(Kg + (size_t)((kt << 6) + 32) * DH_);
    vr0 = *(const uint4*)(Vg + (kt << 6));
    vr1 = *(const uint4*)(Vg + (size_t)32 * N_ + (kt << 6));
  };
  LOADKV(0);

  for (int kt = 0; kt < 16; ++kt) {
    __syncthreads();
    *(uint4*)&Ks[srow][scol]      = kr0;
    *(uint4*)&Ks[srow + 32][scol] = kr1;
    *(uint4*)&Vs[srow][scol]      = vr0;
    *(uint4*)&Vs[srow + 32][scol] = vr1;
    if (kt + 1 < 16) LOADKV(kt + 1);
    __syncthreads();

    f32x4 s[2][4];
#pragma unroll
    for (int m = 0; m < 2; ++m)
#pragma unroll
      for (int n = 0; n < 4; ++n) s[m][n] = zero;
#pragma unroll
    for (int ks = 0; ks < 2; ++ks) {
      bf16x8 kf[4];
#pragma unroll
      for (int n = 0; n < 4; ++n) kf[n] = *(const bf16x8*)&Ks[(n << 4) + lr][(ks << 5) + lk];
#pragma unroll
      for (int m = 0; m < 2; ++m)
#pragma unroll
        for (int n = 0; n < 4; ++n) s[m][n] = mfma16(qf[m][ks], kf[n], s[m][n]);
    }

#pragma unroll
    for (int m = 0; m < 2; ++m)
#pragma unroll
      for (int n = 0; n < 4; ++n)
#pragma unroll
        for (int r = 0; r < 4; ++r) {
          float p = exp2f(s[m][n][r]);
          lsum[m][r] += p;
          Ps[wid][(m << 4) + rbase + r][(n << 4) + lr] = f2bu(p);
        }

#pragma unroll
    for (int ks = 0; ks < 2; ++ks) {
      bf16x8 pf[2], vf[4];
#pragma unroll
      for (int m = 0; m < 2; ++m) pf[m] = *(const bf16x8*)&Ps[wid][(m << 4) + lr][(ks << 5) + lk];
#pragma unroll
      for (int nd = 0; nd < 4; ++nd) vf[nd] = *(const bf16x8*)&Vs[(nd << 4) + lr][(ks << 5) + lk];
#pragma unroll
      for (int m = 0; m < 2; ++m)
#pragma unroll
        for (int nd = 0; nd < 4; ++nd) Oacc[m][nd] = mfma16(pf[m], vf[nd], Oacc[m][nd]);
    }
  }

  int b = bh / H_, h = bh % H_;
#pragma unroll
  for (int m = 0; m < 2; ++m)
#pragma unroll
    for (int r = 0; r < 4; ++r) {
      float sv = lsum[m][r];
#pragma unroll
      for (int off = 1; off < 16; off <<= 1) sv += __shfl_xor(sv, off, 64);
      float inv = 1.0f / sv;
      int row = q0 + (m << 4) + rbase + r;
      size_t orow = ((size_t)b * N_ + row) * F_ + (size_t)h * DH_;
#pragma unroll
      for (int nd = 0; nd < 4; ++nd)
        Aout[orow + (nd << 4) + lr] = f2bu(Oacc[m][nd][r] * inv);
    }
}

extern "C" void kernel_launch(void* const* d_in, const int* in_sizes, int n_in,
                              void* d_out, int out_size, void* d_ws, size_t ws_size,
                              hipStream_t stream) {
  (void)in_sizes; (void)n_in; (void)out_size; (void)ws_size;
  const float* x   = (const float*)d_in[0];
  const float* Wq  = (const float*)d_in[1];
  const float* bq  = (const float*)d_in[2];
  const float* Wk  = (const float*)d_in[3];
  const float* bk  = (const float*)d_in[4];
  const float* Wv  = (const float*)d_in[5];
  const float* bv  = (const float*)d_in[6];
  const float* Wo  = (const float*)d_in[7];
  const float* bo  = (const float*)d_in[8];
  const float* g1  = (const float*)d_in[9];
  const float* bn1 = (const float*)d_in[10];
  const float* g2  = (const float*)d_in[11];
  const float* bn2 = (const float*)d_in[12];
  const float* W1  = (const float*)d_in[13];
  const float* b1  = (const float*)d_in[14];
  const float* W2  = (const float*)d_in[15];
  const float* b2  = (const float*)d_in[16];

  char* ws = (char*)d_ws;
  size_t off = 0;
  auto alloc = [&](size_t bytes) {
    char* p = ws + off;
    off += (bytes + 255) & ~(size_t)255;
    return p;
  };
  u16* Wqkvt = (u16*)alloc((size_t)3 * F_ * F_ * 2);   // [2304][768]
  u16* Wot  = (u16*)alloc((size_t)F_ * F_ * 2);
  u16* W1t  = (u16*)alloc((size_t)MH_ * F_ * 2);
  u16* W2t  = (u16*)alloc((size_t)MH_ * F_ * 2);
  u16* xn  = (u16*)alloc((size_t)MROWS * F_ * 2);            // reused as hn
  u16* qb  = (u16*)alloc((size_t)B_ * H_ * N_ * DH_ * 2);    // q
  u16* kb  = (u16*)alloc((size_t)B_ * H_ * N_ * DH_ * 2);    // k
  u16* vt  = (u16*)alloc((size_t)B_ * H_ * N_ * DH_ * 2);    // V^T (written by qkv)
  u16* pad = (u16*)alloc((size_t)B_ * H_ * N_ * DH_ * 2);    // keeps h1 region 50.3MB
  u16* attn = (u16*)alloc((size_t)MROWS * F_ * 2);
  u16* outb = (u16*)alloc((size_t)MROWS * F_ * 2);           // bf16 residual buffer
  u16* h1 = qb;   // q/k/vt/pad region = 50331648 B = 8192*3072*2, free by then
  u16* hn = xn;
  (void)pad;

  // softmax scale folded into Q: 1/sqrt(768) * log2(e)
  const float QSCALE = 0.052058773227f;

  dim3 blk(256);
  prep_weights<<<dim3(48, 48, 6), blk, 0, stream>>>(Wq, Wk, Wv, Wo, W1, W2,
                                                    Wqkvt, Wot, W1t, W2t);
  ln_to_bf16<float><<<dim3(MROWS), blk, 0, stream>>>(x, g1, bn1, xn);
  gemm_t<0><<<dim3(64 * 18), blk, 0, stream>>>(xn, Wqkvt, bq, bk, bv, qb,
                                               nullptr, 3 * F_, F_, QSCALE);
  attn_fwd<<<dim3(768), blk, 0, stream>>>(qb, kb, vt, attn);
  gemm_s<1><<<dim3(64 * 12), blk, 0, stream>>>(attn, Wot, bo, outb, x, F_, F_);
  ln_to_bf16<u16><<<dim3(MROWS), blk, 0, stream>>>(outb, g2, bn2, hn);
  gemm_t<2><<<dim3(64 * 24), blk, 0, stream>>>(hn, W1t, b1, nullptr, nullptr,
                                               h1, nullptr, MH_, F_, 1.0f);
  gemm_s<3><<<dim3(64 * 12), blk, 0, stream>>>(h1, W2t, b2, d_out, outb, F_, MH_);
}

// Round 16
// 263.744 us; speedup vs baseline: 1.0538x; 1.0538x over previous
//
#include <hip/hip_runtime.h>
#include <math.h>

#define B_ 8
#define N_ 1024
#define F_ 768
#define H_ 12
#define DH_ 64
#define MH_ 3072
#define MROWS (B_ * N_)

typedef unsigned short u16;
typedef unsigned int u32;
typedef __bf16 bf16x8 __attribute__((ext_vector_type(8)));
typedef float f32x4 __attribute__((ext_vector_type(4)));

__device__ inline f32x4 mfma16(bf16x8 a, bf16x8 b, f32x4 c) {
  return __builtin_amdgcn_mfma_f32_16x16x32_bf16(a, b, c, 0, 0, 0);
}

__device__ inline u16 f2bu(float f) {  // float -> bf16 bits, RNE
  u32 b = __builtin_bit_cast(u32, f);
  b += 0x7fffu + ((b >> 16) & 1u);
  return (u16)(b >> 16);
}
__device__ inline float bu2f(u16 u) {
  u32 x = ((u32)u) << 16;
  return __builtin_bit_cast(float, x);
}
// tanh-form GELU, max abs err ~3e-4 vs exact erf form (well under bf16 ulp here)
__device__ inline float gelu_f(float x) {
  float u = x * (0.7978845608028654f + 0.035677408136300125f * x * x);
  float t = exp2f(-2.8853900817779268f * fabsf(u));   // e^{-2|u|}
  float th = (1.0f - t) / (1.0f + t);                 // tanh(|u|)
  th = copysignf(th, u);
  return 0.5f * x * (1.0f + th);
}

#define AS1 __attribute__((address_space(1)))
#define AS3 __attribute__((address_space(3)))
__device__ inline void glds16(const void* g, void* l) {
  __builtin_amdgcn_global_load_lds((const AS1 void*)g, (AS3 void*)l, 16, 0, 0);
}

// ---------------- fused weight prep: 6 transposes fp32->bf16^T ---------------
__global__ __launch_bounds__(256) void prep_weights(
    const float* __restrict__ Wq, const float* __restrict__ Wk,
    const float* __restrict__ Wv, const float* __restrict__ Wo,
    const float* __restrict__ W1, const float* __restrict__ W2,
    u16* __restrict__ Wqkvt, u16* __restrict__ Wot,
    u16* __restrict__ W1t, u16* __restrict__ W2t) {
  __shared__ float tile[64][65];
  int z = blockIdx.z;
  const float* in; u16* out; int R, C;
  if (z == 0)      { in = Wq; out = Wqkvt;                       R = 768;  C = 768; }
  else if (z == 1) { in = Wk; out = Wqkvt + 768 * 768;           R = 768;  C = 768; }
  else if (z == 2) { in = Wv; out = Wqkvt + 2 * 768 * 768;       R = 768;  C = 768; }
  else if (z == 3) { in = Wo; out = Wot;                         R = 768;  C = 768; }
  else if (z == 4) { in = W1; out = W1t;                         R = 768;  C = 3072; }
  else             { in = W2; out = W2t;                         R = 3072; C = 768; }
  int r0 = blockIdx.y << 6, c0 = blockIdx.x << 6;
  if (r0 >= R || c0 >= C) return;
  int t = threadIdx.x;
#pragma unroll
  for (int i = 0; i < 16; ++i) {
    int idx = t + (i << 8);
    int r = idx >> 6, c = idx & 63;
    tile[r][c] = in[(size_t)(r0 + r) * C + (c0 + c)];
  }
  __syncthreads();
#pragma unroll
  for (int i = 0; i < 16; ++i) {
    int idx = t + (i << 8);
    int rr = idx >> 6, cc = idx & 63;
    out[(size_t)(c0 + rr) * R + (r0 + cc)] = f2bu(tile[cc][rr]);
  }
}

// ---------------- bf16 transpose for V: out[c][r] = in[r][c] -----------------
__global__ __launch_bounds__(256) void transpose_v(
    const u16* __restrict__ in, u16* __restrict__ out, int R, int C) {
  __shared__ float tile[64][65];
  size_t base = (size_t)blockIdx.z * (size_t)R * (size_t)C;
  int r0 = blockIdx.y << 6, c0 = blockIdx.x << 6;
  int t = threadIdx.x;
#pragma unroll
  for (int i = 0; i < 16; ++i) {
    int idx = t + (i << 8);
    int r = idx >> 6, c = idx & 63;
    tile[r][c] = bu2f(in[base + (size_t)(r0 + r) * C + (c0 + c)]);
  }
  __syncthreads();
#pragma unroll
  for (int i = 0; i < 16; ++i) {
    int idx = t + (i << 8);
    int rr = idx >> 6, cc = idx & 63;
    out[base + (size_t)(c0 + rr) * R + (r0 + cc)] = f2bu(tile[cc][rr]);
  }
}

// ---------------- LayerNorm (row=768) fp32|bf16 -> bf16 ----------------------
__device__ inline float ldf(const float* p) { return *p; }
__device__ inline float ldf(const u16* p) { return bu2f(*p); }

template <typename Tin>
__global__ __launch_bounds__(256) void ln_to_bf16(
    const Tin* __restrict__ X, const float* __restrict__ gw,
    const float* __restrict__ bw, u16* __restrict__ Y) {
  int row = blockIdx.x;
  int t = threadIdx.x;
  const Tin* xr = X + (size_t)row * F_;
  float v0 = ldf(&xr[t]), v1 = ldf(&xr[t + 256]), v2 = ldf(&xr[t + 512]);
  float s = v0 + v1 + v2;
  float ss = v0 * v0 + v1 * v1 + v2 * v2;
#pragma unroll
  for (int off = 1; off < 64; off <<= 1) {
    s += __shfl_xor(s, off, 64);
    ss += __shfl_xor(ss, off, 64);
  }
  __shared__ float red[8];
  int wid = t >> 6, lane = t & 63;
  if (lane == 0) { red[wid] = s; red[4 + wid] = ss; }
  __syncthreads();
  s = red[0] + red[1] + red[2] + red[3];
  ss = red[4] + red[5] + red[6] + red[7];
  float mu = s * (1.0f / F_);
  float var = ss * (1.0f / F_) - mu * mu;
  float rstd = rsqrtf(var + 1e-5f);
  u16* yr = Y + (size_t)row * F_;
  yr[t] = f2bu((v0 - mu) * rstd * gw[t] + bw[t]);
  yr[t + 256] = f2bu((v1 - mu) * rstd * gw[t + 256] + bw[t + 256]);
  yr[t + 512] = f2bu((v2 - mu) * rstd * gw[t + 512] + bw[t + 512]);
}

// ---------------- unified GEMM: 128x128 block, 4 waves of 64x64, BK=64 -------
// r14 structure: counted-vmcnt 2-slot ring, 8 glds/stage/wave, vmcnt(8)
// (never 0 mid-loop), two raw barriers per K-step, setprio around MFMA.
// LDS [buf][kh][128][32] half-tiles (64B row stride, bank-neutral).
// MODE 0: qkv fused -> bf16 q (scaled) / k / v, all scatter to [B,H,N,DH]
//         (coalesced; V transposed by a separate kernel)
// MODE 1: proj -> bf16 out = acc + bias + resid(fp32 x)
// MODE 2: ffn1 -> bf16 gelu(acc + bias)
// MODE 3: ffn2 -> fp32 gelu(acc + bias) + resid(bf16 outb)
template <int MODE>
__global__ __launch_bounds__(256, 2) void gemm_t(
    const u16* __restrict__ A, const u16* __restrict__ Bt,
    const float* __restrict__ b0, const float* __restrict__ b1,
    const float* __restrict__ b2, void* __restrict__ outp,
    const void* __restrict__ resid, int Ndim, int Kdim, float qscale) {
  __shared__ __attribute__((aligned(16))) u16 As[2][2][128][32];  // [buf][kh]
  __shared__ __attribute__((aligned(16))) u16 Bs[2][2][128][32];
  int t = threadIdx.x;
  int lane = t & 63, wid = t >> 6;

  int nwg = gridDim.x;
  int q8 = nwg >> 3;
  int bid = blockIdx.x;
  int swz = (bid & 7) * q8 + (bid >> 3);
  int nnt = Ndim >> 7;           // 128-wide col tiles
  int mt = swz / nnt, nt = swz - mt * nnt;
  int row0 = mt << 7, col0 = nt << 7;

  int wr = (wid >> 1) << 6;      // 0 / 64
  int wc = (wid & 1) << 6;       // 0 / 64
  int lr = lane & 15, lk = (lane >> 4) << 3;
  int rbase = (lane >> 4) << 2;
  f32x4 zero = {0.f, 0.f, 0.f, 0.f};
  f32x4 acc[4][4];
#pragma unroll
  for (int m = 0; m < 4; ++m)
#pragma unroll
    for (int n = 0; n < 4; ++n) acc[m][n] = zero;

  int srow = (wid << 5) + (lane >> 2);
  int scol = (lane & 3) << 3;
  const u16* Ag = A + (size_t)(row0 + srow) * Kdim + scol;
  const u16* Bg = Bt + (size_t)(col0 + srow) * Kdim + scol;
  char* AsB = (char*)&As[0][0][0][0] + (wid << 11);
  char* BsB = (char*)&Bs[0][0][0][0] + (wid << 11);

  auto STAGE = [&](int buf, int kt) {   // 8 glds per wave
    int ab = buf << 14;
#pragma unroll
    for (int kh = 0; kh < 2; ++kh) {
#pragma unroll
      for (int i = 0; i < 2; ++i) {
        glds16(Ag + (size_t)(i << 4) * Kdim + kt + (kh << 5),
               AsB + ab + (kh << 13) + (i << 10));
        glds16(Bg + (size_t)(i << 4) * Kdim + kt + (kh << 5),
               BsB + ab + (kh << 13) + (i << 10));
      }
    }
  };

  int nk = Kdim >> 6;
  STAGE(0, 0);
  if (nk > 1) STAGE(1, 64);

  for (int ki = 0; ki < nk; ++ki) {
    int buf = ki & 1;
    if (ki + 1 < nk) {
      asm volatile("s_waitcnt vmcnt(8)" ::: "memory");
    } else {
      asm volatile("s_waitcnt vmcnt(0)" ::: "memory");
    }
    __builtin_amdgcn_sched_barrier(0);
    __builtin_amdgcn_s_barrier();           // bar1: tile ki resident
    __builtin_amdgcn_sched_barrier(0);
    bf16x8 af[2][4], bfr[2][4];
#pragma unroll
    for (int h = 0; h < 2; ++h) {
#pragma unroll
      for (int m = 0; m < 4; ++m)
        af[h][m] = *(const bf16x8*)&As[buf][h][wr + (m << 4) + lr][lk];
#pragma unroll
      for (int n = 0; n < 4; ++n)
        bfr[h][n] = *(const bf16x8*)&Bs[buf][h][wc + (n << 4) + lr][lk];
    }
    __builtin_amdgcn_sched_barrier(0);
    __builtin_amdgcn_s_barrier();           // bar2: all reads issued
    __builtin_amdgcn_sched_barrier(0);
    if (ki + 2 < nk) STAGE(buf, (ki + 2) << 6);
    __builtin_amdgcn_s_setprio(1);
#pragma unroll
    for (int h = 0; h < 2; ++h)
#pragma unroll
      for (int m = 0; m < 4; ++m)
#pragma unroll
        for (int n = 0; n < 4; ++n) acc[m][n] = mfma16(af[h][m], bfr[h][n], acc[m][n]);
    __builtin_amdgcn_s_setprio(0);
  }

#pragma unroll
  for (int n = 0; n < 4; ++n) {
    int col = col0 + wc + (n << 4) + lr;
    float bc;
    int sub = 0, hh = 0, dh = 0;
    float sc = 1.0f;
    if constexpr (MODE == 0) {
      sub = (col >= 1536) ? 2 : (col >= 768 ? 1 : 0);
      int c = col - sub * 768;
      bc = (sub == 0) ? b0[c] : (sub == 1 ? b1[c] : b2[c]);
      hh = c >> 6; dh = c & 63;
      sc = (sub == 0) ? qscale : 1.0f;
    } else {
      bc = b0[col];
    }
#pragma unroll
    for (int m = 0; m < 4; ++m) {
#pragma unroll
      for (int r = 0; r < 4; ++r) {
        int row = row0 + wr + (m << 4) + rbase + r;
        float val = acc[m][n][r] + bc;
        if constexpr (MODE == 0) {
          int bb = row >> 10, nn = row & 1023;
          // q (scaled) / k / v, all coalesced [B,H,N,DH]
          ((u16*)outp)[(size_t)sub * 6291456 +
                       ((((size_t)bb * H_ + hh) << 10) + nn) * DH_ + dh] = f2bu(val * sc);
        } else if constexpr (MODE == 1) {
          val += ((const float*)resid)[(size_t)row * Ndim + col];
          ((u16*)outp)[(size_t)row * Ndim + col] = f2bu(val);
        } else if constexpr (MODE == 2) {
          ((u16*)outp)[(size_t)row * Ndim + col] = f2bu(gelu_f(val));
        } else {
          val = gelu_f(val) + bu2f(((const u16*)resid)[(size_t)row * Ndim + col]);
          ((float*)outp)[(size_t)row * Ndim + col] = val;
        }
      }
    }
  }
}

// ---------------- flash attention: no-max softmax, KV chunk 64, T14 split ----
// Q pre-scaled by 1/sqrt(768)*log2(e). Q,K [bh][N][64], Vt [bh][64][N].
__global__ __launch_bounds__(256, 3) void attn_fwd(
    const u16* __restrict__ Q, const u16* __restrict__ K,
    const u16* __restrict__ Vt, u16* __restrict__ Aout) {
  __shared__ __attribute__((aligned(16))) u16 Ks[64][72];
  __shared__ __attribute__((aligned(16))) u16 Vs[64][72];
  __shared__ __attribute__((aligned(16))) u16 Ps[4][32][72];
  int t = threadIdx.x, lane = t & 63, wid = t >> 6;

  int bid = blockIdx.x;                 // 768 blocks
  int swz = (bid & 7) * 96 + (bid >> 3);
  int bh = swz >> 3;
  int qt = swz & 7;
  int q0 = (qt << 7) + (wid << 5);

  int lr = lane & 15, lk = (lane >> 4) << 3;
  int rbase = (lane >> 4) << 2;

  bf16x8 qf[2][2];
#pragma unroll
  for (int m = 0; m < 2; ++m)
#pragma unroll
    for (int ks = 0; ks < 2; ++ks)
      qf[m][ks] = *(const bf16x8*)&Q[((size_t)bh * N_ + q0 + (m << 4) + lr) * DH_ + (ks << 5) + lk];

  float lsum[2][4];
  f32x4 zero = {0.f, 0.f, 0.f, 0.f};
  f32x4 Oacc[2][4];
#pragma unroll
  for (int m = 0; m < 2; ++m) {
#pragma unroll
    for (int r = 0; r < 4; ++r) lsum[m][r] = 0.f;
#pragma unroll
    for (int nd = 0; nd < 4; ++nd) Oacc[m][nd] = zero;
  }

  int srow = t >> 3;            // 0..31
  int scol = (t & 7) << 3;      // 0..56
  const u16* Kg = K + ((size_t)bh * N_ + srow) * DH_ + scol;
  const u16* Vg = Vt + ((size_t)bh * DH_ + srow) * N_ + scol;

  uint4 kr0, kr1, vr0, vr1;
  auto LOADKV = [&](int kt) {
    kr0 = *(const uint4*)(Kg + (size_t)(kt << 6) * DH_);
    kr1 = *(const uint4*)(Kg + (size_t)((kt << 6) + 32) * DH_);
    vr0 = *(const uint4*)(Vg + (kt << 6));
    vr1 = *(const uint4*)(Vg + (size_t)32 * N_ + (kt << 6));
  };
  LOADKV(0);

  for (int kt = 0; kt < 16; ++kt) {
    __syncthreads();
    *(uint4*)&Ks[srow][scol]      = kr0;
    *(uint4*)&Ks[srow + 32][scol] = kr1;
    *(uint4*)&Vs[srow][scol]      = vr0;
    *(uint4*)&Vs[srow + 32][scol] = vr1;
    if (kt + 1 < 16) LOADKV(kt + 1);
    __syncthreads();

    f32x4 s[2][4];
#pragma unroll
    for (int m = 0; m < 2; ++m)
#pragma unroll
      for (int n = 0; n < 4; ++n) s[m][n] = zero;
#pragma unroll
    for (int ks = 0; ks < 2; ++ks) {
      bf16x8 kf[4];
#pragma unroll
      for (int n = 0; n < 4; ++n) kf[n] = *(const bf16x8*)&Ks[(n << 4) + lr][(ks << 5) + lk];
#pragma unroll
      for (int m = 0; m < 2; ++m)
#pragma unroll
        for (int n = 0; n < 4; ++n) s[m][n] = mfma16(qf[m][ks], kf[n], s[m][n]);
    }

#pragma unroll
    for (int m = 0; m < 2; ++m)
#pragma unroll
      for (int n = 0; n < 4; ++n)
#pragma unroll
        for (int r = 0; r < 4; ++r) {
          float p = exp2f(s[m][n][r]);
          lsum[m][r] += p;
          Ps[wid][(m << 4) + rbase + r][(n << 4) + lr] = f2bu(p);
        }

#pragma unroll
    for (int ks = 0; ks < 2; ++ks) {
      bf16x8 pf[2], vf[4];
#pragma unroll
      for (int m = 0; m < 2; ++m) pf[m] = *(const bf16x8*)&Ps[wid][(m << 4) + lr][(ks << 5) + lk];
#pragma unroll
      for (int nd = 0; nd < 4; ++nd) vf[nd] = *(const bf16x8*)&Vs[(nd << 4) + lr][(ks << 5) + lk];
#pragma unroll
      for (int m = 0; m < 2; ++m)
#pragma unroll
        for (int nd = 0; nd < 4; ++nd) Oacc[m][nd] = mfma16(pf[m], vf[nd], Oacc[m][nd]);
    }
  }

  int b = bh / H_, h = bh % H_;
#pragma unroll
  for (int m = 0; m < 2; ++m)
#pragma unroll
    for (int r = 0; r < 4; ++r) {
      float sv = lsum[m][r];
#pragma unroll
      for (int off = 1; off < 16; off <<= 1) sv += __shfl_xor(sv, off, 64);
      float inv = 1.0f / sv;
      int row = q0 + (m << 4) + rbase + r;
      size_t orow = ((size_t)b * N_ + row) * F_ + (size_t)h * DH_;
#pragma unroll
      for (int nd = 0; nd < 4; ++nd)
        Aout[orow + (nd << 4) + lr] = f2bu(Oacc[m][nd][r] * inv);
    }
}

extern "C" void kernel_launch(void* const* d_in, const int* in_sizes, int n_in,
                              void* d_out, int out_size, void* d_ws, size_t ws_size,
                              hipStream_t stream) {
  (void)in_sizes; (void)n_in; (void)out_size; (void)ws_size;
  const float* x   = (const float*)d_in[0];
  const float* Wq  = (const float*)d_in[1];
  const float* bq  = (const float*)d_in[2];
  const float* Wk  = (const float*)d_in[3];
  const float* bk  = (const float*)d_in[4];
  const float* Wv  = (const float*)d_in[5];
  const float* bv  = (const float*)d_in[6];
  const float* Wo  = (const float*)d_in[7];
  const float* bo  = (const float*)d_in[8];
  const float* g1  = (const float*)d_in[9];
  const float* bn1 = (const float*)d_in[10];
  const float* g2  = (const float*)d_in[11];
  const float* bn2 = (const float*)d_in[12];
  const float* W1  = (const float*)d_in[13];
  const float* b1  = (const float*)d_in[14];
  const float* W2  = (const float*)d_in[15];
  const float* b2  = (const float*)d_in[16];

  char* ws = (char*)d_ws;
  size_t off = 0;
  auto alloc = [&](size_t bytes) {
    char* p = ws + off;
    off += (bytes + 255) & ~(size_t)255;
    return p;
  };
  u16* Wqkvt = (u16*)alloc((size_t)3 * F_ * F_ * 2);   // [2304][768]
  u16* Wot  = (u16*)alloc((size_t)F_ * F_ * 2);
  u16* W1t  = (u16*)alloc((size_t)MH_ * F_ * 2);
  u16* W2t  = (u16*)alloc((size_t)MH_ * F_ * 2);
  u16* xn  = (u16*)alloc((size_t)MROWS * F_ * 2);            // reused as hn
  u16* qb  = (u16*)alloc((size_t)B_ * H_ * N_ * DH_ * 2);    // q
  u16* kb  = (u16*)alloc((size_t)B_ * H_ * N_ * DH_ * 2);    // k (qkv writes v next)
  u16* vb  = (u16*)alloc((size_t)B_ * H_ * N_ * DH_ * 2);    // v [B,H,N,DH]
  u16* vt  = (u16*)alloc((size_t)B_ * H_ * N_ * DH_ * 2);    // V^T [B,H,DH,N]
  u16* attn = (u16*)alloc((size_t)MROWS * F_ * 2);
  u16* outb = (u16*)alloc((size_t)MROWS * F_ * 2);           // bf16 residual buffer
  u16* h1 = qb;   // q/k/v/vt region = 50331648 B = 8192*3072*2, free by then
  u16* hn = xn;
  (void)vb;

  // softmax scale folded into Q: 1/sqrt(768) * log2(e)
  const float QSCALE = 0.052058773227f;

  dim3 blk(256);
  prep_weights<<<dim3(48, 48, 6), blk, 0, stream>>>(Wq, Wk, Wv, Wo, W1, W2,
                                                    Wqkvt, Wot, W1t, W2t);
  ln_to_bf16<float><<<dim3(MROWS), blk, 0, stream>>>(x, g1, bn1, xn);
  gemm_t<0><<<dim3(64 * 18), blk, 0, stream>>>(xn, Wqkvt, bq, bk, bv, qb,
                                               nullptr, 3 * F_, F_, QSCALE);
  transpose_v<<<dim3(1, 16, 96), blk, 0, stream>>>(vb, vt, N_, DH_);
  attn_fwd<<<dim3(768), blk, 0, stream>>>(qb, kb, vt, attn);
  gemm_t<1><<<dim3(64 * 6), blk, 0, stream>>>(attn, Wot, bo, nullptr, nullptr,
                                              outb, x, F_, F_, 1.0f);
  ln_to_bf16<u16><<<dim3(MROWS), blk, 0, stream>>>(outb, g2, bn2, hn);
  gemm_t<2><<<dim3(64 * 24), blk, 0, stream>>>(hn, W1t, b1, nullptr, nullptr,
                                               h1, nullptr, MH_, F_, 1.0f);
  gemm_t<3><<<dim3(64 * 6), blk, 0, stream>>>(h1, W2t, b2, nullptr, nullptr,
                                              d_out, outb, F_, MH_, 1.0f);
}